// Round 2
// baseline (434.784 us; speedup 1.0000x reference)
//
#include <hip/hip_runtime.h>
#include <math.h>

#define N 4096
#define DQ 128
#define DIN 64
#define DC 32
#define VSTRIDE 132   // 128 v-cols + 1 p-col + 3 pad (16B-aligned rows)

// ---------------- encode: H0 = concat(x,comms) @ W_enc + b_enc ----------------
__global__ __launch_bounds__(256) void kEncode(const float* __restrict__ x,
    const float* __restrict__ comms, const float* __restrict__ W_enc,
    const float* __restrict__ b_enc, float* __restrict__ H) {
  __shared__ float xs[8][96];
  const int tid = threadIdx.x;
  const int blk = blockIdx.x;                  // 8 rows per block
  if (tid < 128) {                             // stage x: 8x64 contiguous
    const float4 v = *(const float4*)&x[(size_t)blk * 8 * DIN + tid * 4];
    const int idx = tid * 4, r = idx >> 6, c = idx & 63;
    xs[r][c] = v.x; xs[r][c + 1] = v.y; xs[r][c + 2] = v.z; xs[r][c + 3] = v.w;
  } else if (tid < 192) {                      // stage comms: 8x32 contiguous
    const int t = tid - 128;
    const float4 v = *(const float4*)&comms[(size_t)blk * 8 * DC + t * 4];
    const int idx = t * 4, r = idx >> 5, c = idx & 31;
    xs[r][64 + c] = v.x; xs[r][64 + c + 1] = v.y; xs[r][64 + c + 2] = v.z; xs[r][64 + c + 3] = v.w;
  }
  __syncthreads();
  const int r = tid >> 5;
  const int d = (tid & 31) * 4;
  float a0 = b_enc[d], a1 = b_enc[d + 1], a2 = b_enc[d + 2], a3 = b_enc[d + 3];
  for (int c = 0; c < 96; ++c) {
    const float hv = xs[r][c];
    const float4 w = *(const float4*)&W_enc[c * DQ + d];
    a0 += hv * w.x; a1 += hv * w.y; a2 += hv * w.z; a3 += hv * w.w;
  }
  float4 o; o.x = a0; o.y = a1; o.z = a2; o.w = a3;
  *(float4*)&H[((size_t)blk * 8 + r) * DQ + d] = o;
}

// ---------------- sa[i] = H[i,:] . (W_ad[k] @ wa)  (b_ad/b_att cancel in softmax) ----
__global__ __launch_bounds__(256) void kSa(const float* __restrict__ H,
    const float* __restrict__ W_ad_k, const float* __restrict__ wa,
    float* __restrict__ sa) {
  __shared__ float u[DQ];
  const int tid = threadIdx.x;
  if (tid < DQ) {
    float s = 0.f;
    const float* wrow = &W_ad_k[tid * DQ];
    for (int q = 0; q < DQ; ++q) s += wrow[q] * wa[q];
    u[tid] = s;
  }
  __syncthreads();
  const int i = blockIdx.x * 256 + tid;
  const float* hrow = &H[(size_t)i * DQ];
  float s = 0.f;
  for (int d = 0; d < DQ; ++d) s += hrow[d] * u[d];
  sa[i] = s;
}

// ---------------- smax = max_i sa[i] ----------------
__global__ __launch_bounds__(256) void kSmax(const float* __restrict__ sa,
                                             float* __restrict__ smax) {
  __shared__ float red[256];
  float m = -1e30f;
  for (int i = threadIdx.x; i < N; i += 256) m = fmaxf(m, sa[i]);
  red[threadIdx.x] = m;
  __syncthreads();
  for (int s = 128; s > 0; s >>= 1) {
    if (threadIdx.x < s) red[threadIdx.x] = fmaxf(red[threadIdx.x], red[threadIdx.x + s]);
    __syncthreads();
  }
  if (threadIdx.x == 0) smax[0] = red[0];
}

// ---------------- V'[j,:] = p_j * (H[j,:] @ W_av + b_av), col 128 = p_j --------------
__global__ __launch_bounds__(256) void kV(const float* __restrict__ H,
    const float* __restrict__ W_av_k, const float* __restrict__ b_av_k,
    const float* __restrict__ sa, const float* __restrict__ smax,
    float* __restrict__ Vp) {
  __shared__ float hs[8 * DQ];
  const int tid = threadIdx.x;
  const int blk = blockIdx.x;                  // 8 rows per block
  *(float4*)&hs[tid * 4] = *(const float4*)&H[(size_t)blk * 8 * DQ + tid * 4];
  __syncthreads();
  const int r = tid >> 5;
  const int d = (tid & 31) * 4;
  const int j = blk * 8 + r;
  float a0 = b_av_k[d], a1 = b_av_k[d + 1], a2 = b_av_k[d + 2], a3 = b_av_k[d + 3];
  const float* hr = &hs[r * DQ];
  for (int c = 0; c < DQ; ++c) {
    const float hv = hr[c];
    const float4 w = *(const float4*)&W_av_k[c * DQ + d];
    a0 += hv * w.x; a1 += hv * w.y; a2 += hv * w.z; a3 += hv * w.w;
  }
  const float p = __expf(sa[j] - smax[0]);
  float4 o; o.x = p * a0; o.y = p * a1; o.z = p * a2; o.w = p * a3;
  float* vrow = &Vp[(size_t)j * VSTRIDE];
  *(float4*)&vrow[d] = o;
  if (d == 0) { vrow[128] = p; vrow[129] = 0.f; vrow[130] = 0.f; vrow[131] = 0.f; }
}

// ---------------- big GEMM: P[ks][i][d] = sum_{j in chunk} exp(trans[j,i]) * V'[j,d] --
#define BM 64
#define BK 32
__global__ __launch_bounds__(256) void kGemm(const float* __restrict__ trans,
    const float* __restrict__ Vp, float* __restrict__ P, int kchunk) {
  __shared__ float Et[BK][BM];        // exp(trans) tile, [k][i]
  __shared__ float Vt[BK][VSTRIDE];   // V' tile, [k][d]
  const int tid = threadIdx.x;
  const int i0 = blockIdx.x * BM;
  const int k0 = blockIdx.y * kchunk;
  const int tx = tid & 15;            // d: tx*4 and 64+tx*4 (2-way LDS alias = free)
  const int ty = tid >> 4;            // i: ty*4 .. ty*4+3
  float acc[4][8] = {};
  float zacc[4] = {0.f, 0.f, 0.f, 0.f};
  for (int kb = 0; kb < kchunk; kb += BK) {
    __syncthreads();
    // stage Et: 32 rows x 64 cols, exp fused into the load (each element exp'd once)
#pragma unroll
    for (int s = 0; s < 2; ++s) {
      const int f4 = tid + s * 256;                // 0..511
      const int r = f4 >> 4;
      const int c = (f4 & 15) << 2;
      const float4 t4 = *(const float4*)&trans[(size_t)(k0 + kb + r) * N + i0 + c];
      Et[r][c] = __expf(t4.x); Et[r][c + 1] = __expf(t4.y);
      Et[r][c + 2] = __expf(t4.z); Et[r][c + 3] = __expf(t4.w);
    }
    // stage Vt: 32 rows x 33 float4
    for (int f4 = tid; f4 < BK * 33; f4 += 256) {
      const int r = f4 / 33;
      const int c = (f4 - r * 33) << 2;
      *(float4*)&Vt[r][c] = *(const float4*)&Vp[(size_t)(k0 + kb + r) * VSTRIDE + c];
    }
    __syncthreads();
#pragma unroll 4
    for (int kk = 0; kk < BK; ++kk) {
      const float4 e4 = *(const float4*)&Et[kk][ty * 4];
      const float4 va = *(const float4*)&Vt[kk][tx * 4];
      const float4 vb = *(const float4*)&Vt[kk][64 + tx * 4];
      const float pk = Vt[kk][128];
      const float ev[4] = {e4.x, e4.y, e4.z, e4.w};
      const float vv[8] = {va.x, va.y, va.z, va.w, vb.x, vb.y, vb.z, vb.w};
#pragma unroll
      for (int m = 0; m < 4; ++m) {
        zacc[m] += ev[m] * pk;
#pragma unroll
        for (int n = 0; n < 8; ++n) acc[m][n] += ev[m] * vv[n];
      }
    }
  }
#pragma unroll
  for (int m = 0; m < 4; ++m) {
    const int i = i0 + ty * 4 + m;
    float* base = &P[((size_t)blockIdx.y * N + i) * VSTRIDE];
    float4 oa; oa.x = acc[m][0]; oa.y = acc[m][1]; oa.z = acc[m][2]; oa.w = acc[m][3];
    float4 ob; ob.x = acc[m][4]; ob.y = acc[m][5]; ob.z = acc[m][6]; ob.w = acc[m][7];
    *(float4*)&base[tx * 4] = oa;
    *(float4*)&base[64 + tx * 4] = ob;
    if (tx == 0) base[128] = zacc[m];
  }
}

// ---------------- reduce partials + divide by Z -> new H ----------------
__global__ __launch_bounds__(256) void kReduce(const float* __restrict__ P,
    float* __restrict__ Hout, int ksplit) {
  const int tid = threadIdx.x;
  const int i = blockIdx.x * 2 + (tid >> 7);
  const int d = tid & 127;
  float num = 0.f, den = 0.f;
  for (int s = 0; s < ksplit; ++s) {
    const float* base = &P[((size_t)s * N + i) * VSTRIDE];
    num += base[d];
    den += base[128];
  }
  Hout[(size_t)i * DQ + d] = num / den;
}

// ---------------- out = H @ W_dec + b_dec (+mask) ----------------
__global__ __launch_bounds__(256) void kOut(const float* __restrict__ H,
    const float* __restrict__ W_dec, const float* __restrict__ b_dec,
    const int* __restrict__ mask, float* __restrict__ out) {
  __shared__ float w[DQ];
  const int tid = threadIdx.x;
  if (tid < DQ) w[tid] = W_dec[tid];
  __syncthreads();
  const int i = blockIdx.x * 256 + tid;
  float s = b_dec[0];
  const float* hr = &H[(size_t)i * DQ];
  for (int d = 0; d < DQ; ++d) s += hr[d] * w[d];
  out[i] = (mask[i] == 0) ? -INFINITY : s;
}

extern "C" void kernel_launch(void* const* d_in, const int* in_sizes, int n_in,
                              void* d_out, int out_size, void* d_ws, size_t ws_size,
                              hipStream_t stream) {
  (void)in_sizes; (void)n_in; (void)out_size;
  const float* x     = (const float*)d_in[0];
  const float* comms = (const float*)d_in[1];
  const float* trans = (const float*)d_in[2];
  const int*   mask  = (const int*)d_in[3];
  const float* W_enc = (const float*)d_in[4];
  const float* b_enc = (const float*)d_in[5];
  const float* W_ad  = (const float*)d_in[6];
  // d_in[7] = b_ad, d_in[9] = b_att: cancel inside the row softmax
  const float* w_att = (const float*)d_in[8];
  const float* W_av  = (const float*)d_in[10];
  const float* b_av  = (const float*)d_in[11];
  const float* W_dec = (const float*)d_in[12];
  const float* b_dec = (const float*)d_in[13];
  float* out         = (float*)d_out;

  float* ws   = (float*)d_ws;
  float* H0   = ws;                               // N*128
  float* H1   = H0 + (size_t)N * DQ;              // N*128
  float* sa   = H1 + (size_t)N * DQ;              // N
  float* smax = sa + N;                           // 16
  float* Vp   = smax + 16;                        // N*VSTRIDE
  float* P    = Vp + (size_t)N * VSTRIDE;         // ksplit * N * VSTRIDE

  const size_t usedF = (size_t)(P - ws);
  const size_t totF = ws_size / sizeof(float);
  const size_t remF = (totF > usedF) ? (totF - usedF) : 0;
  const size_t cap = remF / ((size_t)N * VSTRIDE);
  int ksplit = (cap >= 8) ? 8 : (cap >= 4) ? 4 : (cap >= 2) ? 2 : 1;

  kEncode<<<N / 8, 256, 0, stream>>>(x, comms, W_enc, b_enc, H0);
  float* Hin = H0; float* Hout = H1;
  for (int k = 0; k < 3; ++k) {
    kSa<<<N / 256, 256, 0, stream>>>(Hin, W_ad + (size_t)k * DQ * DQ,
                                     w_att + (size_t)k * 2 * DQ, sa);
    kSmax<<<1, 256, 0, stream>>>(sa, smax);
    kV<<<N / 8, 256, 0, stream>>>(Hin, W_av + (size_t)k * DQ * DQ,
                                  b_av + (size_t)k * DQ, sa, smax, Vp);
    kGemm<<<dim3(N / BM, ksplit), 256, 0, stream>>>(trans, Vp, P, N / ksplit);
    kReduce<<<N / 2, 256, 0, stream>>>(P, Hout, ksplit);
    float* t = Hin; Hin = Hout; Hout = t;
  }
  kOut<<<N / 256, 256, 0, stream>>>(Hin, W_dec, b_dec, mask, out);
}

// Round 3
// 376.448 us; speedup vs baseline: 1.1550x; 1.1550x over previous
//
#include <hip/hip_runtime.h>
#include <math.h>

#define N 4096
#define DQ 128
#define DIN 64
#define DC 32
#define NT 9          // 9 n-tiles of 16: cols 0..127 = v, col 128 = p (z), 129..143 = 0
#define PSTRIDE 144
#define GBM 64        // i per gemm block (4 waves x 16)
#define KSPLIT 8

typedef __attribute__((ext_vector_type(8))) short short8;
typedef __attribute__((ext_vector_type(4))) float f32x4;

__device__ __forceinline__ unsigned short f2bf(float x) {
  unsigned u = __float_as_uint(x);
  return (unsigned short)((u + 0x7fffu + ((u >> 16) & 1u)) >> 16);
}
__device__ __forceinline__ float bf2f(unsigned short b) {
  return __uint_as_float(((unsigned)b) << 16);
}
// B-fragment swizzle: element (j,d) of V' -> flat index in frag-ordered array.
// Frag layout (16x16x32 bf16 B): lane holds B[k=quad*8+jj][n=lane&15].
__device__ __forceinline__ size_t swz(int j, int d) {
  const int kt = j >> 5, quad = (j & 31) >> 3, jj = j & 7;
  const int lane = quad * 16 + (d & 15), nt = d >> 4;
  return ((size_t)(kt * NT + nt) * 64 + lane) * 8 + jj;
}

// ---------------- encode: H0 = concat(x,comms) @ W_enc + b_enc ----------------
__global__ __launch_bounds__(256) void kEncode(const float* __restrict__ x,
    const float* __restrict__ comms, const float* __restrict__ W_enc,
    const float* __restrict__ b_enc, float* __restrict__ H) {
  __shared__ float xs[8][96];
  const int tid = threadIdx.x;
  const int blk = blockIdx.x;
  if (tid < 128) {
    const float4 v = *(const float4*)&x[(size_t)blk * 8 * DIN + tid * 4];
    const int idx = tid * 4, r = idx >> 6, c = idx & 63;
    xs[r][c] = v.x; xs[r][c + 1] = v.y; xs[r][c + 2] = v.z; xs[r][c + 3] = v.w;
  } else if (tid < 192) {
    const int t = tid - 128;
    const float4 v = *(const float4*)&comms[(size_t)blk * 8 * DC + t * 4];
    const int idx = t * 4, r = idx >> 5, c = idx & 31;
    xs[r][64 + c] = v.x; xs[r][64 + c + 1] = v.y; xs[r][64 + c + 2] = v.z; xs[r][64 + c + 3] = v.w;
  }
  __syncthreads();
  const int r = tid >> 5;
  const int d = (tid & 31) * 4;
  float a0 = b_enc[d], a1 = b_enc[d + 1], a2 = b_enc[d + 2], a3 = b_enc[d + 3];
  for (int c = 0; c < 96; ++c) {
    const float hv = xs[r][c];
    const float4 w = *(const float4*)&W_enc[c * DQ + d];
    a0 += hv * w.x; a1 += hv * w.y; a2 += hv * w.z; a3 += hv * w.w;
  }
  float4 o; o.x = a0; o.y = a1; o.z = a2; o.w = a3;
  *(float4*)&H[((size_t)blk * 8 + r) * DQ + d] = o;
}

// ---------------- round 0: sa[i] = H[i,:] . (W_ad[k] @ wa) ----------------
__global__ __launch_bounds__(256) void kSa0(const float* __restrict__ H,
    const float* __restrict__ W_ad_k, const float* __restrict__ wa,
    float* __restrict__ sa) {
  __shared__ float u[DQ];
  const int tid = threadIdx.x;
  if (tid < DQ) {
    float s = 0.f;
    const float* wrow = &W_ad_k[tid * DQ];
    for (int q = 0; q < DQ; ++q) s += wrow[q] * wa[q];
    u[tid] = s;
  }
  __syncthreads();
  const int i = blockIdx.x * 256 + tid;
  const float* hrow = &H[(size_t)i * DQ];
  float s = 0.f;
  for (int d = 0; d < DQ; ++d) s += hrow[d] * u[d];
  sa[i] = s;
}

// ---------------- rounds 1,2: fuse P-reduce -> H, sa  (2 rows per block) -----
__global__ __launch_bounds__(256) void kSaR(const float* __restrict__ P,
    const float* __restrict__ W_ad_k, const float* __restrict__ wa,
    float* __restrict__ Hout, float* __restrict__ sa) {
  __shared__ float u[DQ];
  __shared__ float red[256];
  const int tid = threadIdx.x;
  if (tid < DQ) {
    float s = 0.f;
    const float* wrow = &W_ad_k[tid * DQ];
    for (int q = 0; q < DQ; ++q) s += wrow[q] * wa[q];
    u[tid] = s;
  }
  const int d = tid & 127;
  const int i = blockIdx.x * 2 + (tid >> 7);
  float num = 0.f, den = 0.f;
#pragma unroll
  for (int s = 0; s < KSPLIT; ++s) {
    const float* b = &P[((size_t)s * N + i) * PSTRIDE];
    num += b[d];
    den += b[128];
  }
  const float h = num / den;
  Hout[(size_t)i * DQ + d] = h;
  __syncthreads();
  red[tid] = h * u[d];
  __syncthreads();
  for (int st = 64; st > 0; st >>= 1) {
    if (d < st) red[tid] += red[tid + st];
    __syncthreads();
  }
  if (d == 0) sa[i] = red[tid];
}

// ---------------- smax = max_i sa[i] ----------------
__global__ __launch_bounds__(256) void kSmax(const float* __restrict__ sa,
                                             float* __restrict__ smax) {
  __shared__ float red[256];
  float m = -1e30f;
  for (int i = threadIdx.x; i < N; i += 256) m = fmaxf(m, sa[i]);
  red[threadIdx.x] = m;
  __syncthreads();
  for (int s = 128; s > 0; s >>= 1) {
    if (threadIdx.x < s) red[threadIdx.x] = fmaxf(red[threadIdx.x], red[threadIdx.x + s]);
    __syncthreads();
  }
  if (threadIdx.x == 0) smax[0] = red[0];
}

// -------- V' = p*(H@W_av+b_av); split to bf16 hi/lo in MFMA B-frag order -----
__global__ __launch_bounds__(256) void kVS(const float* __restrict__ H,
    const float* __restrict__ W_av_k, const float* __restrict__ b_av_k,
    const float* __restrict__ sa, const float* __restrict__ smax,
    unsigned short* __restrict__ Vhi, unsigned short* __restrict__ Vlo) {
  __shared__ float hs[8 * DQ];
  const int tid = threadIdx.x;
  const int blk = blockIdx.x;
  *(float4*)&hs[tid * 4] = *(const float4*)&H[(size_t)blk * 8 * DQ + tid * 4];
  __syncthreads();
  const int r = tid >> 5;
  const int d4 = (tid & 31) * 4;
  const int j = blk * 8 + r;
  float a[4] = {b_av_k[d4], b_av_k[d4 + 1], b_av_k[d4 + 2], b_av_k[d4 + 3]};
  const float* hr = &hs[r * DQ];
  for (int c = 0; c < DQ; ++c) {
    const float hv = hr[c];
    const float4 w = *(const float4*)&W_av_k[c * DQ + d4];
    a[0] += hv * w.x; a[1] += hv * w.y; a[2] += hv * w.z; a[3] += hv * w.w;
  }
  const float p = __expf(sa[j] - smax[0]);
#pragma unroll
  for (int e = 0; e < 4; ++e) {
    const float val = p * a[e];
    const unsigned short hi = f2bf(val);
    const unsigned short lo = f2bf(val - bf2f(hi));
    const size_t ix = swz(j, d4 + e);
    Vhi[ix] = hi; Vlo[ix] = lo;
  }
  if (d4 == 0) {                       // z column: p at d=128, zeros 129..143
    const unsigned short phi = f2bf(p);
    const unsigned short plo = f2bf(p - bf2f(phi));
    const size_t ix = swz(j, 128);
    Vhi[ix] = phi; Vlo[ix] = plo;
    for (int dd = 129; dd < 144; ++dd) {
      const size_t iz = swz(j, dd);
      Vhi[iz] = 0; Vlo[iz] = 0;
    }
  }
}

// ---- MFMA GEMM: P[s][i][d] = sum_j exp(trans[j,i]) * V'[j,d], bf16 split-3 ----
__global__ __launch_bounds__(256) void kGemmM(const float* __restrict__ trans,
    const unsigned short* __restrict__ Vhi, const unsigned short* __restrict__ Vlo,
    float* __restrict__ P) {
  const int tid = threadIdx.x;
  const int w = tid >> 6, lane = tid & 63;
  const int quad = lane >> 4, l15 = lane & 15;
  const int i0 = blockIdx.x * GBM + w * 16;      // this wave's 16 i-rows
  const int kchunk = N / KSPLIT;                 // 512
  const int k0 = blockIdx.y * kchunk;
  const int nsteps = kchunk / 32;                // 16

  f32x4 acc[NT];
#pragma unroll
  for (int nt = 0; nt < NT; ++nt) acc[nt] = (f32x4){0.f, 0.f, 0.f, 0.f};

  // A: lane loads trans[(k0 + quad*8 + jj)][i0 + l15] for jj=0..7 (one kstep)
  const float* aptr = trans + (size_t)(k0 + quad * 8) * N + i0 + l15;
  float araw[8];
#pragma unroll
  for (int j = 0; j < 8; ++j) araw[j] = aptr[(size_t)j * N];

  for (int t = 0; t < nsteps; ++t) {
    float anext[8];
    if (t + 1 < nsteps) {
      const float* ap2 = aptr + (size_t)(t + 1) * 32 * N;
#pragma unroll
      for (int j = 0; j < 8; ++j) anext[j] = ap2[(size_t)j * N];
    }
    // exp + hi/lo split (each trans element exp'd exactly once per round)
    unsigned short hb[8], lb[8];
#pragma unroll
    for (int j = 0; j < 8; ++j) {
      const float e = __expf(araw[j]);
      hb[j] = f2bf(e);
      lb[j] = f2bf(e - bf2f(hb[j]));
    }
    const short8 ah = {(short)hb[0], (short)hb[1], (short)hb[2], (short)hb[3],
                       (short)hb[4], (short)hb[5], (short)hb[6], (short)hb[7]};
    const short8 al = {(short)lb[0], (short)lb[1], (short)lb[2], (short)lb[3],
                       (short)lb[4], (short)lb[5], (short)lb[6], (short)lb[7]};
    const int kt = (k0 >> 5) + t;
    const unsigned short* bh = Vhi + ((size_t)kt * NT * 64 + lane) * 8;
    const unsigned short* bl = Vlo + ((size_t)kt * NT * 64 + lane) * 8;
#pragma unroll
    for (int nt = 0; nt < NT; ++nt) {
      const short8 bhv = *(const short8*)(bh + (size_t)nt * 512);
      const short8 blv = *(const short8*)(bl + (size_t)nt * 512);
      acc[nt] = __builtin_amdgcn_mfma_f32_16x16x32_bf16(ah, bhv, acc[nt], 0, 0, 0);
      acc[nt] = __builtin_amdgcn_mfma_f32_16x16x32_bf16(ah, blv, acc[nt], 0, 0, 0);
      acc[nt] = __builtin_amdgcn_mfma_f32_16x16x32_bf16(al, bhv, acc[nt], 0, 0, 0);
    }
#pragma unroll
    for (int j = 0; j < 8; ++j) araw[j] = anext[j];
  }
  // C layout: col = lane&15, row = quad*4 + reg
  float* Pb = P + (size_t)blockIdx.y * N * PSTRIDE;
#pragma unroll
  for (int nt = 0; nt < NT; ++nt) {
#pragma unroll
    for (int r = 0; r < 4; ++r) {
      const int i = i0 + quad * 4 + r;
      Pb[(size_t)i * PSTRIDE + nt * 16 + l15] = acc[nt][r];
    }
  }
}

// ---------------- final: out[i] = (sum_d num[i][d] W_dec[d]) / den + b_dec ----
__global__ __launch_bounds__(256) void kOutR(const float* __restrict__ P,
    const float* __restrict__ W_dec, const float* __restrict__ b_dec,
    const int* __restrict__ mask, float* __restrict__ out) {
  __shared__ float red[256];
  const int tid = threadIdx.x;
  const int d = tid & 127;
  const int i = blockIdx.x * 2 + (tid >> 7);
  float num = 0.f, den = 0.f;
#pragma unroll
  for (int s = 0; s < KSPLIT; ++s) {
    const float* b = &P[((size_t)s * N + i) * PSTRIDE];
    num += b[d];
    den += b[128];
  }
  red[tid] = num * W_dec[d];
  __syncthreads();
  for (int st = 64; st > 0; st >>= 1) {
    if (d < st) red[tid] += red[tid + st];
    __syncthreads();
  }
  if (d == 0) out[i] = (mask[i] == 0) ? -INFINITY : red[tid] / den + b_dec[0];
}

extern "C" void kernel_launch(void* const* d_in, const int* in_sizes, int n_in,
                              void* d_out, int out_size, void* d_ws, size_t ws_size,
                              hipStream_t stream) {
  (void)in_sizes; (void)n_in; (void)out_size; (void)ws_size;
  const float* x     = (const float*)d_in[0];
  const float* comms = (const float*)d_in[1];
  const float* trans = (const float*)d_in[2];
  const int*   mask  = (const int*)d_in[3];
  const float* W_enc = (const float*)d_in[4];
  const float* b_enc = (const float*)d_in[5];
  const float* W_ad  = (const float*)d_in[6];
  // d_in[7]=b_ad, d_in[9]=b_att cancel inside the row softmax
  const float* w_att = (const float*)d_in[8];
  const float* W_av  = (const float*)d_in[10];
  const float* b_av  = (const float*)d_in[11];
  const float* W_dec = (const float*)d_in[12];
  const float* b_dec = (const float*)d_in[13];
  float* out         = (float*)d_out;

  char* ws = (char*)d_ws;
  float* H0   = (float*)ws;                                   ws += (size_t)N * DQ * 4;
  float* H1   = (float*)ws;                                   ws += (size_t)N * DQ * 4;
  float* sa   = (float*)ws;                                   ws += (size_t)N * 4;
  float* smax = (float*)ws;                                   ws += 64;
  unsigned short* Vhi = (unsigned short*)ws;                  ws += (size_t)N * PSTRIDE * 2;
  unsigned short* Vlo = (unsigned short*)ws;                  ws += (size_t)N * PSTRIDE * 2;
  float* P    = (float*)ws;   // KSPLIT * N * PSTRIDE fp32 = 18.9 MB

  kEncode<<<N / 8, 256, 0, stream>>>(x, comms, W_enc, b_enc, H0);
  float* Hin = H0; float* Hnext = H1;
  for (int k = 0; k < 3; ++k) {
    if (k == 0) {
      kSa0<<<N / 256, 256, 0, stream>>>(Hin, W_ad, w_att, sa);
    } else {
      kSaR<<<N / 2, 256, 0, stream>>>(P, W_ad + (size_t)k * DQ * DQ,
                                      w_att + (size_t)k * 2 * DQ, Hnext, sa);
      float* t = Hin; Hin = Hnext; Hnext = t;
    }
    kSmax<<<1, 256, 0, stream>>>(sa, smax);
    kVS<<<N / 8, 256, 0, stream>>>(Hin, W_av + (size_t)k * DQ * DQ,
                                   b_av + (size_t)k * DQ, sa, smax, Vhi, Vlo);
    kGemmM<<<dim3(N / GBM, KSPLIT), 256, 0, stream>>>(trans, Vhi, Vlo, P);
  }
  kOutR<<<N / 2, 256, 0, stream>>>(P, W_dec, b_dec, mask, out);
}

// Round 4
// 288.809 us; speedup vs baseline: 1.5054x; 1.3034x over previous
//
#include <hip/hip_runtime.h>
#include <math.h>

#define N 4096
#define DQ 128
#define DIN 64
#define DC 32
#define NT 9          // 9 n-tiles of 16: cols 0..127 = v, col 128 = p (z), 129..143 = 0
#define PSTRIDE 144
#define GBM 64        // i per gemm block (4 waves x 16)

typedef __attribute__((ext_vector_type(8))) short short8;
typedef __attribute__((ext_vector_type(4))) float f32x4;

__device__ __forceinline__ unsigned short f2bf(float x) {
  unsigned u = __float_as_uint(x);
  return (unsigned short)((u + 0x7fffu + ((u >> 16) & 1u)) >> 16);
}
__device__ __forceinline__ float bf2f(unsigned short b) {
  return __uint_as_float(((unsigned)b) << 16);
}
// B-fragment swizzle: element (j,d) of V' -> flat index in frag-ordered array.
// Frag layout (16x16x32 bf16 B): lane holds B[k=quad*8+jj][n=lane&15].
__device__ __forceinline__ size_t swz(int j, int d) {
  const int kt = j >> 5, quad = (j & 31) >> 3, jj = j & 7;
  const int lane = quad * 16 + (d & 15), nt = d >> 4;
  return ((size_t)(kt * NT + nt) * 64 + lane) * 8 + jj;
}

// ---- shared epilogue: p*(h@W_av+b_av) -> bf16 hi/lo swizzled, + z column ----
__device__ __forceinline__ void v_phase(const float* hs_row, float p,
    const float* __restrict__ W_av_k, const float* __restrict__ b_av_k,
    int j, int d4, unsigned short* __restrict__ Vhi, unsigned short* __restrict__ Vlo) {
  float a[4] = {b_av_k[d4], b_av_k[d4 + 1], b_av_k[d4 + 2], b_av_k[d4 + 3]};
  for (int c = 0; c < DQ; ++c) {
    const float hv = hs_row[c];
    const float4 w = *(const float4*)&W_av_k[c * DQ + d4];
    a[0] += hv * w.x; a[1] += hv * w.y; a[2] += hv * w.z; a[3] += hv * w.w;
  }
#pragma unroll
  for (int e = 0; e < 4; ++e) {
    const float val = p * a[e];
    const unsigned short hi = f2bf(val);
    const unsigned short lo = f2bf(val - bf2f(hi));
    const size_t ix = swz(j, d4 + e);
    Vhi[ix] = hi; Vlo[ix] = lo;
  }
  if (d4 == 0) {                       // z column: p at d=128, zeros 129..143
    const unsigned short phi = f2bf(p);
    const unsigned short plo = f2bf(p - bf2f(phi));
    const size_t ix = swz(j, 128);
    Vhi[ix] = phi; Vlo[ix] = plo;
    for (int dd = 129; dd < 144; ++dd) {
      const size_t iz = swz(j, dd);
      Vhi[iz] = 0; Vlo[iz] = 0;
    }
  }
}

// ---- round 0: encode + sa + p + V' fused (8 rows per block) ----
__global__ __launch_bounds__(256) void kVS0(const float* __restrict__ x,
    const float* __restrict__ comms, const float* __restrict__ W_enc,
    const float* __restrict__ b_enc, const float* __restrict__ W_ad_k,
    const float* __restrict__ wa, const float* __restrict__ W_av_k,
    const float* __restrict__ b_av_k,
    unsigned short* __restrict__ Vhi, unsigned short* __restrict__ Vlo) {
  __shared__ float xs[8][96];
  __shared__ float hs[8][DQ];
  __shared__ float u[DQ];
  __shared__ float pb[8];
  const int tid = threadIdx.x;
  const int blk = blockIdx.x;
  if (tid < 128) {
    const float4 v = *(const float4*)&x[(size_t)blk * 8 * DIN + tid * 4];
    const int idx = tid * 4, r = idx >> 6, c = idx & 63;
    xs[r][c] = v.x; xs[r][c + 1] = v.y; xs[r][c + 2] = v.z; xs[r][c + 3] = v.w;
  } else if (tid < 192) {
    const int t = tid - 128;
    const float4 v = *(const float4*)&comms[(size_t)blk * 8 * DC + t * 4];
    const int idx = t * 4, r = idx >> 5, c = idx & 31;
    xs[r][64 + c] = v.x; xs[r][64 + c + 1] = v.y; xs[r][64 + c + 2] = v.z; xs[r][64 + c + 3] = v.w;
  }
  if (tid < DQ) {
    float s = 0.f;
    const float* wrow = &W_ad_k[tid * DQ];
    for (int q = 0; q < DQ; ++q) s += wrow[q] * wa[q];
    u[tid] = s;
  }
  __syncthreads();
  const int r = tid >> 5;
  const int c32 = tid & 31;
  const int d4 = c32 * 4;
  const int j = blk * 8 + r;
  {
    float a0 = b_enc[d4], a1 = b_enc[d4 + 1], a2 = b_enc[d4 + 2], a3 = b_enc[d4 + 3];
    for (int c = 0; c < 96; ++c) {
      const float hv = xs[r][c];
      const float4 w = *(const float4*)&W_enc[c * DQ + d4];
      a0 += hv * w.x; a1 += hv * w.y; a2 += hv * w.z; a3 += hv * w.w;
    }
    hs[r][d4] = a0; hs[r][d4 + 1] = a1; hs[r][d4 + 2] = a2; hs[r][d4 + 3] = a3;
  }
  __syncthreads();
  float part = 0.f;
  for (int c = c32; c < DQ; c += 32) part += hs[r][c] * u[c];
#pragma unroll
  for (int m = 16; m > 0; m >>= 1) part += __shfl_xor(part, m, 32);
  if (c32 == 0) pb[r] = __expf(part);
  __syncthreads();
  v_phase(hs[r], pb[r], W_av_k, b_av_k, j, d4, Vhi, Vlo);
}

// ---- rounds 1,2: P-reduce -> h + sa + p + V' fused (8 rows per block) ----
__global__ __launch_bounds__(256) void kVSR(const float* __restrict__ P,
    const float* __restrict__ W_ad_k, const float* __restrict__ wa,
    const float* __restrict__ W_av_k, const float* __restrict__ b_av_k,
    unsigned short* __restrict__ Vhi, unsigned short* __restrict__ Vlo,
    int ksplit) {
  __shared__ float hs[8][DQ];
  __shared__ float u[DQ];
  __shared__ float pb[8];
  const int tid = threadIdx.x;
  const int r = tid >> 5;
  const int c32 = tid & 31;
  const int d4 = c32 * 4;
  const int j = blockIdx.x * 8 + r;
  if (tid < DQ) {
    float s = 0.f;
    const float* wrow = &W_ad_k[tid * DQ];
    for (int q = 0; q < DQ; ++q) s += wrow[q] * wa[q];
    u[tid] = s;
  }
  float4 num = {0.f, 0.f, 0.f, 0.f};
  float den = 0.f;
  for (int s = 0; s < ksplit; ++s) {
    const float* b = &P[((size_t)s * N + j) * PSTRIDE];
    const float4 v = *(const float4*)&b[d4];
    num.x += v.x; num.y += v.y; num.z += v.z; num.w += v.w;
    den += b[128];
  }
  const float inv = 1.f / den;
  hs[r][d4] = num.x * inv; hs[r][d4 + 1] = num.y * inv;
  hs[r][d4 + 2] = num.z * inv; hs[r][d4 + 3] = num.w * inv;
  __syncthreads();
  float part = 0.f;
  for (int c = c32; c < DQ; c += 32) part += hs[r][c] * u[c];
#pragma unroll
  for (int m = 16; m > 0; m >>= 1) part += __shfl_xor(part, m, 32);
  if (c32 == 0) pb[r] = __expf(part);
  __syncthreads();
  v_phase(hs[r], pb[r], W_av_k, b_av_k, j, d4, Vhi, Vlo);
}

// ---- MFMA GEMM: P[s][i][d] = sum_j exp(trans[j,i]) * V'[j,d], bf16 split-3 ----
__global__ __launch_bounds__(256) void kGemmM(const float* __restrict__ trans,
    const unsigned short* __restrict__ Vhi, const unsigned short* __restrict__ Vlo,
    float* __restrict__ P, int kchunk) {
  const int tid = threadIdx.x;
  const int w = tid >> 6, lane = tid & 63;
  const int quad = lane >> 4, l15 = lane & 15;
  const int i0 = blockIdx.x * GBM + w * 16;      // this wave's 16 i-rows
  const int k0 = blockIdx.y * kchunk;
  const int nsteps = kchunk >> 5;

  f32x4 acc[NT];
#pragma unroll
  for (int nt = 0; nt < NT; ++nt) acc[nt] = (f32x4){0.f, 0.f, 0.f, 0.f};

  // A: lane loads trans[(k0 + quad*8 + jj)][i0 + l15] for jj=0..7 (one kstep)
  const float* aptr = trans + (size_t)(k0 + quad * 8) * N + i0 + l15;
  float araw[8];
#pragma unroll
  for (int jj = 0; jj < 8; ++jj) araw[jj] = aptr[(size_t)jj * N];

  for (int t = 0; t < nsteps; ++t) {
    float anext[8];
    if (t + 1 < nsteps) {
      const float* ap2 = aptr + (size_t)(t + 1) * 32 * N;
#pragma unroll
      for (int jj = 0; jj < 8; ++jj) anext[jj] = ap2[(size_t)jj * N];
    }
    unsigned short hb[8], lb[8];
#pragma unroll
    for (int jj = 0; jj < 8; ++jj) {
      const float e = __expf(araw[jj]);
      hb[jj] = f2bf(e);
      lb[jj] = f2bf(e - bf2f(hb[jj]));
    }
    const short8 ah = {(short)hb[0], (short)hb[1], (short)hb[2], (short)hb[3],
                       (short)hb[4], (short)hb[5], (short)hb[6], (short)hb[7]};
    const short8 al = {(short)lb[0], (short)lb[1], (short)lb[2], (short)lb[3],
                       (short)lb[4], (short)lb[5], (short)lb[6], (short)lb[7]};
    const int kt = (k0 >> 5) + t;
    const unsigned short* bh = Vhi + ((size_t)kt * NT * 64 + lane) * 8;
    const unsigned short* bl = Vlo + ((size_t)kt * NT * 64 + lane) * 8;
#pragma unroll
    for (int nt = 0; nt < NT; ++nt) {
      const short8 bhv = *(const short8*)(bh + (size_t)nt * 512);
      const short8 blv = *(const short8*)(bl + (size_t)nt * 512);
      acc[nt] = __builtin_amdgcn_mfma_f32_16x16x32_bf16(ah, bhv, acc[nt], 0, 0, 0);
      acc[nt] = __builtin_amdgcn_mfma_f32_16x16x32_bf16(ah, blv, acc[nt], 0, 0, 0);
      acc[nt] = __builtin_amdgcn_mfma_f32_16x16x32_bf16(al, bhv, acc[nt], 0, 0, 0);
    }
#pragma unroll
    for (int jj = 0; jj < 8; ++jj) araw[jj] = anext[jj];
  }
  // C layout: col = lane&15, row = quad*4 + reg
  float* Pb = P + (size_t)blockIdx.y * N * PSTRIDE;
#pragma unroll
  for (int nt = 0; nt < NT; ++nt) {
#pragma unroll
    for (int r = 0; r < 4; ++r) {
      const int i = i0 + quad * 4 + r;
      Pb[(size_t)i * PSTRIDE + nt * 16 + l15] = acc[nt][r];
    }
  }
}

// ---- final: out[i] = (sum_d num[i][d] W_dec[d]) / den + b_dec ----
__global__ __launch_bounds__(256) void kOutR(const float* __restrict__ P,
    const float* __restrict__ W_dec, const float* __restrict__ b_dec,
    const int* __restrict__ mask, float* __restrict__ out, int ksplit) {
  __shared__ float red[256];
  const int tid = threadIdx.x;
  const int d = tid & 127;
  const int i = blockIdx.x * 2 + (tid >> 7);
  float num = 0.f, den = 0.f;
  for (int s = 0; s < ksplit; ++s) {
    const float* b = &P[((size_t)s * N + i) * PSTRIDE];
    num += b[d];
    den += b[128];
  }
  red[tid] = num * W_dec[d];
  __syncthreads();
  for (int st = 64; st > 0; st >>= 1) {
    if (d < st) red[tid] += red[tid + st];
    __syncthreads();
  }
  if (d == 0) out[i] = (mask[i] == 0) ? -INFINITY : red[tid] / den + b_dec[0];
}

extern "C" void kernel_launch(void* const* d_in, const int* in_sizes, int n_in,
                              void* d_out, int out_size, void* d_ws, size_t ws_size,
                              hipStream_t stream) {
  (void)in_sizes; (void)n_in; (void)out_size;
  const float* x     = (const float*)d_in[0];
  const float* comms = (const float*)d_in[1];
  const float* trans = (const float*)d_in[2];
  const int*   mask  = (const int*)d_in[3];
  const float* W_enc = (const float*)d_in[4];
  const float* b_enc = (const float*)d_in[5];
  const float* W_ad  = (const float*)d_in[6];
  // d_in[7]=b_ad, d_in[9]=b_att cancel inside the row softmax
  const float* w_att = (const float*)d_in[8];
  const float* W_av  = (const float*)d_in[10];
  const float* b_av  = (const float*)d_in[11];
  const float* W_dec = (const float*)d_in[12];
  const float* b_dec = (const float*)d_in[13];
  float* out         = (float*)d_out;

  char* ws = (char*)d_ws;
  unsigned short* Vhi = (unsigned short*)ws;  ws += (size_t)N * PSTRIDE * 2;
  unsigned short* Vlo = (unsigned short*)ws;  ws += (size_t)N * PSTRIDE * 2;
  float* P = (float*)ws;
  const size_t fixedB = (size_t)N * PSTRIDE * 4;          // Vhi+Vlo
  const size_t perB   = (size_t)N * PSTRIDE * 4;          // one P split (fp32)
  const int ksplit = (ws_size >= fixedB + 16 * perB) ? 16 : 8;
  const int kchunk = N / ksplit;

  for (int k = 0; k < 3; ++k) {
    const float* W_ad_k = W_ad + (size_t)k * DQ * DQ;
    const float* wa     = w_att + (size_t)k * 2 * DQ;
    const float* W_av_k = W_av + (size_t)k * DQ * DQ;
    const float* b_av_k = b_av + (size_t)k * DQ;
    if (k == 0) {
      kVS0<<<N / 8, 256, 0, stream>>>(x, comms, W_enc, b_enc, W_ad_k, wa,
                                      W_av_k, b_av_k, Vhi, Vlo);
    } else {
      kVSR<<<N / 8, 256, 0, stream>>>(P, W_ad_k, wa, W_av_k, b_av_k,
                                      Vhi, Vlo, ksplit);
    }
    kGemmM<<<dim3(N / GBM, ksplit), 256, 0, stream>>>(trans, Vhi, Vlo, P, kchunk);
  }
  kOutR<<<N / 2, 256, 0, stream>>>(P, W_dec, b_dec, mask, out, ksplit);
}